// Round 4
// baseline (3842.619 us; speedup 1.0000x reference)
//
#include <hip/hip_runtime.h>

#define Vv 32000
#define Ee 256
#define Hh 512
#define Ll 128
#define Bb 16
#define Tt 128
#define G3 1536   // 3*H
#define NWG 64    // persistent scan workgroups

typedef __attribute__((ext_vector_type(8))) short short8;
typedef __attribute__((ext_vector_type(4))) float f32x4;

__device__ __forceinline__ float sigmoidf_(float x) { return 1.f / (1.f + __expf(-x)); }

// f32 -> bf16 round-to-nearest-even
__device__ __forceinline__ unsigned short f2bf(float f) {
  unsigned int u = __float_as_uint(f);
  u = (u + 0x7fffu + ((u >> 16) & 1u)) >> 16;
  return (unsigned short)u;
}

// ---------------- zero helper ----------------
__global__ void k_zero(float* __restrict__ p, int n) {
  int i = blockIdx.x * 256 + threadIdx.x;
  if (i < n) p[i] = 0.f;
}

// zero outputs[:, 0, :]
__global__ void k_zero_first(float* __restrict__ out) {
  int idx = blockIdx.x * 256 + threadIdx.x;
  if (idx < Bb * Vv) {
    int b = idx / Vv, v = idx % Vv;
    out[(size_t)b * Tt * Vv + v] = 0.f;
  }
}

// ---------------- f32 -> bf16 bulk convert ----------------
__global__ void k_cvt_bf16(const float* __restrict__ in, unsigned short* __restrict__ out,
                           int n4) {
  int i = blockIdx.x * 256 + threadIdx.x;
  if (i < n4) {
    float4 v = ((const float4*)in)[i];
    ushort4 o;
    o.x = f2bf(v.x); o.y = f2bf(v.y); o.z = f2bf(v.z); o.w = f2bf(v.w);
    ((ushort4*)out)[i] = o;
  }
}

// ---------------- transpose: in [R][C] -> out [C][R] ----------------
__global__ void k_transpose(const float* __restrict__ in, float* __restrict__ out,
                            int R, int C) {
  __shared__ float tile[32][33];
  int c = blockIdx.x * 32 + threadIdx.x;
  int r0 = blockIdx.y * 32;
  for (int i = threadIdx.y; i < 32; i += 8)
    tile[i][threadIdx.x] = in[(size_t)(r0 + i) * C + c];
  __syncthreads();
  int r = r0 + threadIdx.x;
  int c0 = blockIdx.x * 32;
  for (int i = threadIdx.y; i < 32; i += 8)
    out[(size_t)(c0 + i) * R + r] = tile[threadIdx.x][i];
}

// ---------------- gx = emb[x] @ W_ih^T + b_ih ----------------
__global__ void k_gx(const int* __restrict__ x, const float* __restrict__ emb,
                     const float* __restrict__ WihT, const float* __restrict__ b_ih,
                     float* __restrict__ gx) {
  int g = blockIdx.y * 256 + threadIdx.x;
  int mt = blockIdx.x;
  __shared__ float A[16][Ee];
  for (int i = 0; i < 16; i++) {
    int m = mt * 16 + i;
    int t = m >> 4, b = m & 15;
    int tok = x[b * Tt + t];
    A[i][threadIdx.x] = emb[(size_t)tok * Ee + threadIdx.x];
  }
  __syncthreads();
  float acc[16];
  float bg = b_ih[g];
#pragma unroll
  for (int i = 0; i < 16; i++) acc[i] = bg;
#pragma unroll 4
  for (int e = 0; e < Ee; e++) {
    float w = WihT[(size_t)e * G3 + g];
#pragma unroll
    for (int i = 0; i < 16; i++) acc[i] = fmaf(A[i][e], w, acc[i]);
  }
#pragma unroll
  for (int i = 0; i < 16; i++)
    gx[(size_t)(mt * 16 + i) * G3 + g] = acc[i];
}

// ---------------- persistent GRU scan (fence-free sc1 barrier) ----------------
__global__ void __launch_bounds__(256) k_scan(
    const float* __restrict__ Whh,   // [3H][H]
    const float* __restrict__ bhh,   // [3H]
    const float* __restrict__ gx,    // [nsteps*16][3H]
    float* __restrict__ hbuf,        // [2][16][H]
    unsigned short* __restrict__ hseq,  // [nsteps][16][H] bf16, or nullptr
    int nsteps, int* __restrict__ flags) {
  __shared__ float h_lds[Bb * Hh];            // 32 KB
  __shared__ float scratch[4][8][3][Bb];      // 6 KB
  const int tid = threadIdx.x;
  const int wg = blockIdx.x;
  const int jloc = tid & 7;
  const int ks = tid >> 3;    // 0..31
  const int j = wg * 8 + jloc;
  const int k0 = ks * 16;

  // load recurrent weights into registers (once)
  float wr[16], wz[16], wn[16];
  {
    const float4* R = (const float4*)(Whh + (size_t)j * Hh + k0);
    const float4* Z = (const float4*)(Whh + (size_t)(Hh + j) * Hh + k0);
    const float4* N = (const float4*)(Whh + (size_t)(2 * Hh + j) * Hh + k0);
#pragma unroll
    for (int q = 0; q < 4; ++q) {
      float4 a = R[q]; wr[4*q] = a.x; wr[4*q+1] = a.y; wr[4*q+2] = a.z; wr[4*q+3] = a.w;
      float4 b = Z[q]; wz[4*q] = b.x; wz[4*q+1] = b.y; wz[4*q+2] = b.z; wz[4*q+3] = b.w;
      float4 c = N[q]; wn[4*q] = c.x; wn[4*q+1] = c.y; wn[4*q+2] = c.z; wn[4*q+3] = c.w;
    }
  }
  float bhr = 0.f, bhz = 0.f, bhn = 0.f;
  if (tid < 128) { bhr = bhh[j]; bhz = bhh[Hh + j]; bhn = bhh[2 * Hh + j]; }

  for (int t = 0; t < nsteps; ++t) {
    // stage h -> LDS via coherence-point (sc1) loads: always fresh, no invalidate
    {
      int* hsrc = (int*)(hbuf + (size_t)(t & 1) * (Bb * Hh));
#pragma unroll
      for (int i = 0; i < 32; ++i) {
        int v = __hip_atomic_load(hsrc + tid + 256 * i, __ATOMIC_RELAXED,
                                  __HIP_MEMORY_SCOPE_AGENT);
        h_lds[tid + 256 * i] = __int_as_float(v);
      }
    }
    float xr = 0.f, xz = 0.f, xn = 0.f;
    if (tid < 128) {
      const float* gp = gx + (size_t)(t * Bb + ks) * G3 + j;
      xr = gp[0]; xz = gp[Hh]; xn = gp[2 * Hh];
    }
    __syncthreads();

    float accR[Bb], accZ[Bb], accN[Bb];
#pragma unroll
    for (int b = 0; b < Bb; ++b) { accR[b] = 0.f; accZ[b] = 0.f; accN[b] = 0.f; }
#pragma unroll
    for (int b = 0; b < Bb; ++b) {
      const float4* hp = (const float4*)(h_lds + b * Hh + k0);
#pragma unroll
      for (int q = 0; q < 4; ++q) {
        float4 hv = hp[q];
        accR[b] = fmaf(wr[4*q+0], hv.x, accR[b]);
        accR[b] = fmaf(wr[4*q+1], hv.y, accR[b]);
        accR[b] = fmaf(wr[4*q+2], hv.z, accR[b]);
        accR[b] = fmaf(wr[4*q+3], hv.w, accR[b]);
        accZ[b] = fmaf(wz[4*q+0], hv.x, accZ[b]);
        accZ[b] = fmaf(wz[4*q+1], hv.y, accZ[b]);
        accZ[b] = fmaf(wz[4*q+2], hv.z, accZ[b]);
        accZ[b] = fmaf(wz[4*q+3], hv.w, accZ[b]);
        accN[b] = fmaf(wn[4*q+0], hv.x, accN[b]);
        accN[b] = fmaf(wn[4*q+1], hv.y, accN[b]);
        accN[b] = fmaf(wn[4*q+2], hv.z, accN[b]);
        accN[b] = fmaf(wn[4*q+3], hv.w, accN[b]);
      }
    }
#pragma unroll
    for (int b = 0; b < Bb; ++b) {
      accR[b] += __shfl_xor(accR[b], 8, 64);
      accR[b] += __shfl_xor(accR[b], 16, 64);
      accR[b] += __shfl_xor(accR[b], 32, 64);
      accZ[b] += __shfl_xor(accZ[b], 8, 64);
      accZ[b] += __shfl_xor(accZ[b], 16, 64);
      accZ[b] += __shfl_xor(accZ[b], 32, 64);
      accN[b] += __shfl_xor(accN[b], 8, 64);
      accN[b] += __shfl_xor(accN[b], 16, 64);
      accN[b] += __shfl_xor(accN[b], 32, 64);
    }
    if ((ks & 7) == 0) {
      const int wv = tid >> 6;
#pragma unroll
      for (int b = 0; b < Bb; ++b) {
        scratch[wv][jloc][0][b] = accR[b];
        scratch[wv][jloc][1][b] = accZ[b];
        scratch[wv][jloc][2][b] = accN[b];
      }
    }
    __syncthreads();

    float* hdst = hbuf + (size_t)((t + 1) & 1) * (Bb * Hh);
    if (tid < 128) {
      const int b = ks;
      float ar = scratch[0][jloc][0][b] + scratch[1][jloc][0][b] +
                 scratch[2][jloc][0][b] + scratch[3][jloc][0][b] + bhr;
      float az = scratch[0][jloc][1][b] + scratch[1][jloc][1][b] +
                 scratch[2][jloc][1][b] + scratch[3][jloc][1][b] + bhz;
      float an = scratch[0][jloc][2][b] + scratch[1][jloc][2][b] +
                 scratch[2][jloc][2][b] + scratch[3][jloc][2][b] + bhn;
      float r = sigmoidf_(xr + ar);
      float u = sigmoidf_(xz + az);
      float n = tanhf(xn + r * an);
      float hold = h_lds[b * Hh + j];
      float hnew = (1.f - u) * n + u * hold;
      // write-through to the coherence point (LLC) — no fence needed
      __hip_atomic_store((int*)hdst + b * Hh + j, __float_as_int(hnew),
                         __ATOMIC_RELAXED, __HIP_MEMORY_SCOPE_AGENT);
      if (hseq) hseq[((size_t)t * Bb + b) * Hh + j] = f2bf(hnew);
    }

    // ---- fence-free device barrier ----
    if (t < nsteps - 1) {
      asm volatile("s_waitcnt vmcnt(0)" ::: "memory");  // per-wave: stores at LLC
      __syncthreads();
      if (tid == 0)
        __hip_atomic_store(&flags[wg], t + 1, __ATOMIC_RELAXED, __HIP_MEMORY_SCOPE_AGENT);
      if (tid < NWG) {
        while (__hip_atomic_load(&flags[tid], __ATOMIC_RELAXED,
                                 __HIP_MEMORY_SCOPE_AGENT) < t + 1) {}
      }
      __syncthreads();
    }
  }
}

// ---------------- z = h_last @ fc_enc_W^T + b ----------------
__global__ void k_z(const float* __restrict__ h, const float* __restrict__ W,
                    const float* __restrict__ bias, float* __restrict__ zws,
                    float* __restrict__ zout) {
  int b = blockIdx.x;
  int l = threadIdx.x;  // 128
  __shared__ float hsh[Hh];
  for (int i = threadIdx.x; i < Hh; i += 128) hsh[i] = h[b * Hh + i];
  __syncthreads();
  float acc = bias[l];
#pragma unroll 4
  for (int k = 0; k < Hh; k++) acc = fmaf(hsh[k], W[(size_t)l * Hh + k], acc);
  zws[b * Ll + l] = acc;
  zout[b * Ll + l] = acc;
}

// ---------------- hid0 = tanh(z @ fc_dec_W^T + b) ----------------
__global__ void k_hid0(const float* __restrict__ z, const float* __restrict__ W,
                       const float* __restrict__ bias, float* __restrict__ h0) {
  int b = blockIdx.x;
  int j = threadIdx.x;  // 512
  __shared__ float zsh[Ll];
  if (threadIdx.x < Ll) zsh[threadIdx.x] = z[b * Ll + threadIdx.x];
  __syncthreads();
  float acc = bias[j];
#pragma unroll 4
  for (int l = 0; l < Ll; l++) acc = fmaf(zsh[l], W[(size_t)j * Ll + l], acc);
  h0[b * Hh + j] = tanhf(acc);
}

// ---------------- logits via MFMA bf16 ----------------
template <bool BF16W>
__global__ void __launch_bounds__(256) k_logits_mfma(
    const unsigned short* __restrict__ Abf,  // [2048][512] bf16
    const unsigned short* __restrict__ Wbf,  // [32000][512] bf16 (if BF16W)
    const float* __restrict__ Wf,            // [32000][512] f32 (fallback)
    const float* __restrict__ bias, float* __restrict__ out) {
  const int tid = threadIdx.x;
  const int wid = tid >> 6, lane = tid & 63;
  const int ln = lane & 15, hi = lane >> 4;
  const int n0 = blockIdx.x * 64;
  const int m0 = blockIdx.y * 256 + wid * 64;
  f32x4 acc[4][4];
#pragma unroll
  for (int mi = 0; mi < 4; ++mi)
#pragma unroll
    for (int ni = 0; ni < 4; ++ni) acc[mi][ni] = (f32x4)0.f;

  const unsigned short* ap = Abf + (size_t)(m0 + ln) * Hh + hi * 8;
  const unsigned short* bp16 = Wbf + (size_t)(n0 + ln) * Hh + hi * 8;
  const float* bp32 = Wf + (size_t)(n0 + ln) * Hh + hi * 8;

  for (int kt = 0; kt < 16; ++kt) {
    short8 a[4], b[4];
#pragma unroll
    for (int mi = 0; mi < 4; ++mi)
      a[mi] = *(const short8*)(ap + (size_t)mi * 16 * Hh + kt * 32);
#pragma unroll
    for (int ni = 0; ni < 4; ++ni) {
      if (BF16W) {
        b[ni] = *(const short8*)(bp16 + (size_t)ni * 16 * Hh + kt * 32);
      } else {
        const float* q = bp32 + (size_t)ni * 16 * Hh + kt * 32;
        short8 tv;
#pragma unroll
        for (int e = 0; e < 8; ++e) tv[e] = (short)f2bf(q[e]);
        b[ni] = tv;
      }
    }
#pragma unroll
    for (int mi = 0; mi < 4; ++mi)
#pragma unroll
      for (int ni = 0; ni < 4; ++ni)
        acc[mi][ni] = __builtin_amdgcn_mfma_f32_16x16x32_bf16(a[mi], b[ni], acc[mi][ni], 0, 0, 0);
  }

#pragma unroll
  for (int ni = 0; ni < 4; ++ni) {
    int n = n0 + ni * 16 + ln;
    float bv = bias[n];
#pragma unroll
    for (int mi = 0; mi < 4; ++mi) {
      int mbase = m0 + mi * 16 + hi * 4;
#pragma unroll
      for (int r = 0; r < 4; ++r) {
        int m = mbase + r;
        if (m < 2032) {
          int t = m >> 4, bb = m & 15;
          out[((size_t)(bb * Tt + 1 + t)) * Vv + n] = acc[mi][ni][r] + bv;
        }
      }
    }
  }
}

extern "C" void kernel_launch(void* const* d_in, const int* in_sizes, int n_in,
                              void* d_out, int out_size, void* d_ws, size_t ws_size,
                              hipStream_t stream) {
  const int* x = (const int*)d_in[0];
  const float* enc_emb = (const float*)d_in[1];
  const float* enc_Wih = (const float*)d_in[2];
  const float* enc_bih = (const float*)d_in[3];
  const float* enc_Whh = (const float*)d_in[4];
  const float* enc_bhh = (const float*)d_in[5];
  const float* fc_enc_W = (const float*)d_in[6];
  const float* fc_enc_b = (const float*)d_in[7];
  const float* fc_dec_W = (const float*)d_in[8];
  const float* fc_dec_b = (const float*)d_in[9];
  const float* dec_emb = (const float*)d_in[10];
  const float* dec_Wih = (const float*)d_in[11];
  const float* dec_bih = (const float*)d_in[12];
  const float* dec_Whh = (const float*)d_in[13];
  const float* dec_bhh = (const float*)d_in[14];
  const float* dec_fcW = (const float*)d_in[15];
  const float* dec_fcb = (const float*)d_in[16];
  float* out = (float*)d_out;

  float* ws = (float*)d_ws;
  size_t off = 0;
  float* wihT_e = ws + off; off += 393216;
  float* wihT_d = ws + off; off += 393216;
  float* gx_e = ws + off; off += 3145728;
  float* gx_d = ws + off; off += 3121152;
  float* hbuf = ws + off; off += 16384;
  float* zbuf = ws + off; off += 2048;
  int* flags_e = (int*)(ws + off); off += 512;
  int* flags_d = flags_e + 128;
  unsigned short* hseq_bf = (unsigned short*)(ws + off); off += 524288;
  size_t wbf_elems = (size_t)Vv * Hh;
  bool use_wbf = (off + wbf_elems / 2) * sizeof(float) <= ws_size;
  unsigned short* wbf = (unsigned short*)(ws + off);

  // init
  hipMemsetAsync(flags_e, 0, 512 * sizeof(int), stream);
  k_zero<<<(Bb * Hh + 255) / 256, 256, 0, stream>>>(hbuf, Bb * Hh);
  k_zero_first<<<(Bb * Vv + 255) / 256, 256, 0, stream>>>(out);

  if (use_wbf)
    k_cvt_bf16<<<(int)((wbf_elems / 4 + 255) / 256), 256, 0, stream>>>(
        dec_fcW, wbf, (int)(wbf_elems / 4));

  dim3 tb(32, 8);
  k_transpose<<<dim3(256 / 32, 1536 / 32), tb, 0, stream>>>(enc_Wih, wihT_e, 1536, 256);
  k_transpose<<<dim3(256 / 32, 1536 / 32), tb, 0, stream>>>(dec_Wih, wihT_d, 1536, 256);

  k_gx<<<dim3(128, 6), 256, 0, stream>>>(x, enc_emb, wihT_e, enc_bih, gx_e);
  k_gx<<<dim3(127, 6), 256, 0, stream>>>(x, dec_emb, wihT_d, dec_bih, gx_d);

  // encoder scan
  k_scan<<<NWG, 256, 0, stream>>>(enc_Whh, enc_bhh, gx_e, hbuf,
                                  (unsigned short*)nullptr, 128, flags_e);

  k_z<<<16, 128, 0, stream>>>(hbuf, fc_enc_W, fc_enc_b, zbuf, out + (size_t)Bb * Tt * Vv);
  k_hid0<<<16, 512, 0, stream>>>(zbuf, fc_dec_W, fc_dec_b, hbuf);

  // decoder scan
  k_scan<<<NWG, 256, 0, stream>>>(dec_Whh, dec_bhh, gx_d, hbuf, hseq_bf, 127, flags_d);

  // logits
  if (use_wbf)
    k_logits_mfma<true><<<dim3(Vv / 64, 8), 256, 0, stream>>>(hseq_bf, wbf, dec_fcW,
                                                              dec_fcb, out);
  else
    k_logits_mfma<false><<<dim3(Vv / 64, 8), 256, 0, stream>>>(hseq_bf, (unsigned short*)nullptr,
                                                               dec_fcW, dec_fcb, out);
}

// Round 5
// 1968.418 us; speedup vs baseline: 1.9521x; 1.9521x over previous
//
#include <hip/hip_runtime.h>

#define Vv 32000
#define Ee 256
#define Hh 512
#define Ll 128
#define Bb 16
#define Tt 128
#define G3 1536   // 3*H
#define NWG 64    // persistent scan workgroups

typedef __attribute__((ext_vector_type(8))) short short8;
typedef __attribute__((ext_vector_type(4))) float f32x4;

__device__ __forceinline__ float sigmoidf_(float x) { return 1.f / (1.f + __expf(-x)); }

// f32 -> bf16 round-to-nearest-even
__device__ __forceinline__ unsigned short f2bf(float f) {
  unsigned int u = __float_as_uint(f);
  u = (u + 0x7fffu + ((u >> 16) & 1u)) >> 16;
  return (unsigned short)u;
}

// ---------------- zero helper ----------------
__global__ void k_zero(float* __restrict__ p, int n) {
  int i = blockIdx.x * 256 + threadIdx.x;
  if (i < n) p[i] = 0.f;
}

// zero outputs[:, 0, :]
__global__ void k_zero_first(float* __restrict__ out) {
  int idx = blockIdx.x * 256 + threadIdx.x;
  if (idx < Bb * Vv) {
    int b = idx / Vv, v = idx % Vv;
    out[(size_t)b * Tt * Vv + v] = 0.f;
  }
}

// ---------------- f32 -> bf16 bulk convert ----------------
__global__ void k_cvt_bf16(const float* __restrict__ in, unsigned short* __restrict__ out,
                           int n4) {
  int i = blockIdx.x * 256 + threadIdx.x;
  if (i < n4) {
    float4 v = ((const float4*)in)[i];
    ushort4 o;
    o.x = f2bf(v.x); o.y = f2bf(v.y); o.z = f2bf(v.z); o.w = f2bf(v.w);
    ((ushort4*)out)[i] = o;
  }
}

// ---------------- transpose: in [R][C] -> out [C][R] ----------------
__global__ void k_transpose(const float* __restrict__ in, float* __restrict__ out,
                            int R, int C) {
  __shared__ float tile[32][33];
  int c = blockIdx.x * 32 + threadIdx.x;
  int r0 = blockIdx.y * 32;
  for (int i = threadIdx.y; i < 32; i += 8)
    tile[i][threadIdx.x] = in[(size_t)(r0 + i) * C + c];
  __syncthreads();
  int r = r0 + threadIdx.x;
  int c0 = blockIdx.x * 32;
  for (int i = threadIdx.y; i < 32; i += 8)
    out[(size_t)(c0 + i) * R + r] = tile[threadIdx.x][i];
}

// ---------------- gx = emb[x] @ W_ih^T + b_ih ----------------
__global__ void k_gx(const int* __restrict__ x, const float* __restrict__ emb,
                     const float* __restrict__ WihT, const float* __restrict__ b_ih,
                     float* __restrict__ gx) {
  int g = blockIdx.y * 256 + threadIdx.x;
  int mt = blockIdx.x;
  __shared__ float A[16][Ee];
  for (int i = 0; i < 16; i++) {
    int m = mt * 16 + i;
    int t = m >> 4, b = m & 15;
    int tok = x[b * Tt + t];
    A[i][threadIdx.x] = emb[(size_t)tok * Ee + threadIdx.x];
  }
  __syncthreads();
  float acc[16];
  float bg = b_ih[g];
#pragma unroll
  for (int i = 0; i < 16; i++) acc[i] = bg;
#pragma unroll 4
  for (int e = 0; e < Ee; e++) {
    float w = WihT[(size_t)e * G3 + g];
#pragma unroll
    for (int i = 0; i < 16; i++) acc[i] = fmaf(A[i][e], w, acc[i]);
  }
#pragma unroll
  for (int i = 0; i < 16; i++)
    gx[(size_t)(mt * 16 + i) * G3 + g] = acc[i];
}

// ---------------- persistent GRU scan (counting barrier, fence-free sc1 exchange) ----------------
__global__ void __launch_bounds__(256) k_scan(
    const float* __restrict__ Whh,   // [3H][H]
    const float* __restrict__ bhh,   // [3H]
    const float* __restrict__ gx,    // [nsteps*16][3H]
    float* __restrict__ hbuf,        // [2][16][H]
    unsigned short* __restrict__ hseq,  // [nsteps][16][H] bf16, or nullptr
    int nsteps, int* __restrict__ cnt) {
  __shared__ float h_lds[Bb * Hh];            // 32 KB
  __shared__ float scratch[4][8][3][Bb];      // 6 KB
  const int tid = threadIdx.x;
  const int wg = blockIdx.x;
  const int jloc = tid & 7;
  const int ks = tid >> 3;    // 0..31
  const int j = wg * 8 + jloc;
  const int k0 = ks * 16;

  // load recurrent weights into registers (once)
  float wr[16], wz[16], wn[16];
  {
    const float4* R = (const float4*)(Whh + (size_t)j * Hh + k0);
    const float4* Z = (const float4*)(Whh + (size_t)(Hh + j) * Hh + k0);
    const float4* N = (const float4*)(Whh + (size_t)(2 * Hh + j) * Hh + k0);
#pragma unroll
    for (int q = 0; q < 4; ++q) {
      float4 a = R[q]; wr[4*q] = a.x; wr[4*q+1] = a.y; wr[4*q+2] = a.z; wr[4*q+3] = a.w;
      float4 b = Z[q]; wz[4*q] = b.x; wz[4*q+1] = b.y; wz[4*q+2] = b.z; wz[4*q+3] = b.w;
      float4 c = N[q]; wn[4*q] = c.x; wn[4*q+1] = c.y; wn[4*q+2] = c.z; wn[4*q+3] = c.w;
    }
  }
  float bhr = 0.f, bhz = 0.f, bhn = 0.f;
  if (tid < 128) { bhr = bhh[j]; bhz = bhh[Hh + j]; bhn = bhh[2 * Hh + j]; }

  // gx for step 0
  float xr = 0.f, xz = 0.f, xn = 0.f;
  if (tid < 128) {
    const float* gp = gx + (size_t)ks * G3 + j;
    xr = gp[0]; xz = gp[Hh]; xn = gp[2 * Hh];
  }

  for (int t = 0; t < nsteps; ++t) {
    // ---- stage h -> LDS via wide coherent loads (LLC-fresh, no invalidate) ----
    {
      const f32x4* hsrc = (const f32x4*)(hbuf + (size_t)(t & 1) * (Bb * Hh));
      f32x4 hv[8];
#pragma unroll
      for (int i = 0; i < 8; ++i) {
        const f32x4* p = hsrc + tid + 256 * i;
        asm volatile("global_load_dwordx4 %0, %1, off sc1" : "=v"(hv[i]) : "v"(p));
      }
      asm volatile("s_waitcnt vmcnt(0)" ::: "memory");
      f32x4* hl = (f32x4*)h_lds;
#pragma unroll
      for (int i = 0; i < 8; ++i) hl[tid + 256 * i] = hv[i];
    }
    __syncthreads();

    float accR[Bb], accZ[Bb], accN[Bb];
#pragma unroll
    for (int b = 0; b < Bb; ++b) { accR[b] = 0.f; accZ[b] = 0.f; accN[b] = 0.f; }
#pragma unroll
    for (int b = 0; b < Bb; ++b) {
      const float4* hp = (const float4*)(h_lds + b * Hh + k0);
#pragma unroll
      for (int q = 0; q < 4; ++q) {
        float4 hv = hp[q];
        accR[b] = fmaf(wr[4*q+0], hv.x, accR[b]);
        accR[b] = fmaf(wr[4*q+1], hv.y, accR[b]);
        accR[b] = fmaf(wr[4*q+2], hv.z, accR[b]);
        accR[b] = fmaf(wr[4*q+3], hv.w, accR[b]);
        accZ[b] = fmaf(wz[4*q+0], hv.x, accZ[b]);
        accZ[b] = fmaf(wz[4*q+1], hv.y, accZ[b]);
        accZ[b] = fmaf(wz[4*q+2], hv.z, accZ[b]);
        accZ[b] = fmaf(wz[4*q+3], hv.w, accZ[b]);
        accN[b] = fmaf(wn[4*q+0], hv.x, accN[b]);
        accN[b] = fmaf(wn[4*q+1], hv.y, accN[b]);
        accN[b] = fmaf(wn[4*q+2], hv.z, accN[b]);
        accN[b] = fmaf(wn[4*q+3], hv.w, accN[b]);
      }
    }
#pragma unroll
    for (int b = 0; b < Bb; ++b) {
      accR[b] += __shfl_xor(accR[b], 8, 64);
      accR[b] += __shfl_xor(accR[b], 16, 64);
      accR[b] += __shfl_xor(accR[b], 32, 64);
      accZ[b] += __shfl_xor(accZ[b], 8, 64);
      accZ[b] += __shfl_xor(accZ[b], 16, 64);
      accZ[b] += __shfl_xor(accZ[b], 32, 64);
      accN[b] += __shfl_xor(accN[b], 8, 64);
      accN[b] += __shfl_xor(accN[b], 16, 64);
      accN[b] += __shfl_xor(accN[b], 32, 64);
    }
    if ((ks & 7) == 0) {
      const int wv = tid >> 6;
#pragma unroll
      for (int b = 0; b < Bb; ++b) {
        scratch[wv][jloc][0][b] = accR[b];
        scratch[wv][jloc][1][b] = accZ[b];
        scratch[wv][jloc][2][b] = accN[b];
      }
    }
    __syncthreads();

    float* hdst = hbuf + (size_t)((t + 1) & 1) * (Bb * Hh);
    if (tid < 128) {
      const int b = ks;
      float ar = scratch[0][jloc][0][b] + scratch[1][jloc][0][b] +
                 scratch[2][jloc][0][b] + scratch[3][jloc][0][b] + bhr;
      float az = scratch[0][jloc][1][b] + scratch[1][jloc][1][b] +
                 scratch[2][jloc][1][b] + scratch[3][jloc][1][b] + bhz;
      float an = scratch[0][jloc][2][b] + scratch[1][jloc][2][b] +
                 scratch[2][jloc][2][b] + scratch[3][jloc][2][b] + bhn;
      float r = sigmoidf_(xr + ar);
      float u = sigmoidf_(xz + az);
      float n = tanhf(xn + r * an);
      float hold = h_lds[b * Hh + j];
      float hnew = (1.f - u) * n + u * hold;
      // publish to coherence point (LLC)
      __hip_atomic_store((int*)hdst + b * Hh + j, __float_as_int(hnew),
                         __ATOMIC_RELAXED, __HIP_MEMORY_SCOPE_AGENT);
      if (hseq) hseq[((size_t)t * Bb + b) * Hh + j] = f2bf(hnew);
    }

    // ---- counting barrier (single counter, single poller per WG) ----
    if (t < nsteps - 1) {
      asm volatile("s_waitcnt vmcnt(0)" ::: "memory");  // per-wave: publishes at LLC
      __syncthreads();
      if (tid == 0)
        __hip_atomic_fetch_add(cnt, 1, __ATOMIC_RELAXED, __HIP_MEMORY_SCOPE_AGENT);
      // prefetch next step's gx under the barrier wait (normal cached loads)
      if (tid < 128) {
        const float* gp = gx + (size_t)((t + 1) * Bb + ks) * G3 + j;
        xr = gp[0]; xz = gp[Hh]; xn = gp[2 * Hh];
      }
      if (tid == 0) {
        const int target = NWG * (t + 1);
        int v;
        do {
          asm volatile("global_load_dword %0, %1, off sc1\n\ts_waitcnt vmcnt(0)"
                       : "=v"(v) : "v"(cnt) : "memory");
        } while (v < target);
      }
      __syncthreads();
    }
  }
}

// ---------------- z = h_last @ fc_enc_W^T + b ----------------
__global__ void k_z(const float* __restrict__ h, const float* __restrict__ W,
                    const float* __restrict__ bias, float* __restrict__ zws,
                    float* __restrict__ zout) {
  int b = blockIdx.x;
  int l = threadIdx.x;  // 128
  __shared__ float hsh[Hh];
  for (int i = threadIdx.x; i < Hh; i += 128) hsh[i] = h[b * Hh + i];
  __syncthreads();
  float acc = bias[l];
#pragma unroll 4
  for (int k = 0; k < Hh; k++) acc = fmaf(hsh[k], W[(size_t)l * Hh + k], acc);
  zws[b * Ll + l] = acc;
  zout[b * Ll + l] = acc;
}

// ---------------- hid0 = tanh(z @ fc_dec_W^T + b) ----------------
__global__ void k_hid0(const float* __restrict__ z, const float* __restrict__ W,
                       const float* __restrict__ bias, float* __restrict__ h0) {
  int b = blockIdx.x;
  int j = threadIdx.x;  // 512
  __shared__ float zsh[Ll];
  if (threadIdx.x < Ll) zsh[threadIdx.x] = z[b * Ll + threadIdx.x];
  __syncthreads();
  float acc = bias[j];
#pragma unroll 4
  for (int l = 0; l < Ll; l++) acc = fmaf(zsh[l], W[(size_t)j * Ll + l], acc);
  h0[b * Hh + j] = tanhf(acc);
}

// ---------------- logits via MFMA bf16 ----------------
template <bool BF16W>
__global__ void __launch_bounds__(256) k_logits_mfma(
    const unsigned short* __restrict__ Abf,  // [2048][512] bf16
    const unsigned short* __restrict__ Wbf,  // [32000][512] bf16 (if BF16W)
    const float* __restrict__ Wf,            // [32000][512] f32 (fallback)
    const float* __restrict__ bias, float* __restrict__ out) {
  const int tid = threadIdx.x;
  const int wid = tid >> 6, lane = tid & 63;
  const int ln = lane & 15, hi = lane >> 4;
  const int n0 = blockIdx.x * 64;
  const int m0 = blockIdx.y * 256 + wid * 64;
  f32x4 acc[4][4];
#pragma unroll
  for (int mi = 0; mi < 4; ++mi)
#pragma unroll
    for (int ni = 0; ni < 4; ++ni) acc[mi][ni] = (f32x4)0.f;

  const unsigned short* ap = Abf + (size_t)(m0 + ln) * Hh + hi * 8;
  const unsigned short* bp16 = Wbf + (size_t)(n0 + ln) * Hh + hi * 8;
  const float* bp32 = Wf + (size_t)(n0 + ln) * Hh + hi * 8;

  for (int kt = 0; kt < 16; ++kt) {
    short8 a[4], b[4];
#pragma unroll
    for (int mi = 0; mi < 4; ++mi)
      a[mi] = *(const short8*)(ap + (size_t)mi * 16 * Hh + kt * 32);
#pragma unroll
    for (int ni = 0; ni < 4; ++ni) {
      if (BF16W) {
        b[ni] = *(const short8*)(bp16 + (size_t)ni * 16 * Hh + kt * 32);
      } else {
        const float* q = bp32 + (size_t)ni * 16 * Hh + kt * 32;
        short8 tv;
#pragma unroll
        for (int e = 0; e < 8; ++e) tv[e] = (short)f2bf(q[e]);
        b[ni] = tv;
      }
    }
#pragma unroll
    for (int mi = 0; mi < 4; ++mi)
#pragma unroll
      for (int ni = 0; ni < 4; ++ni)
        acc[mi][ni] = __builtin_amdgcn_mfma_f32_16x16x32_bf16(a[mi], b[ni], acc[mi][ni], 0, 0, 0);
  }

#pragma unroll
  for (int ni = 0; ni < 4; ++ni) {
    int n = n0 + ni * 16 + ln;
    float bv = bias[n];
#pragma unroll
    for (int mi = 0; mi < 4; ++mi) {
      int mbase = m0 + mi * 16 + hi * 4;
#pragma unroll
      for (int r = 0; r < 4; ++r) {
        int m = mbase + r;
        if (m < 2032) {
          int t = m >> 4, bb = m & 15;
          out[((size_t)(bb * Tt + 1 + t)) * Vv + n] = acc[mi][ni][r] + bv;
        }
      }
    }
  }
}

extern "C" void kernel_launch(void* const* d_in, const int* in_sizes, int n_in,
                              void* d_out, int out_size, void* d_ws, size_t ws_size,
                              hipStream_t stream) {
  const int* x = (const int*)d_in[0];
  const float* enc_emb = (const float*)d_in[1];
  const float* enc_Wih = (const float*)d_in[2];
  const float* enc_bih = (const float*)d_in[3];
  const float* enc_Whh = (const float*)d_in[4];
  const float* enc_bhh = (const float*)d_in[5];
  const float* fc_enc_W = (const float*)d_in[6];
  const float* fc_enc_b = (const float*)d_in[7];
  const float* fc_dec_W = (const float*)d_in[8];
  const float* fc_dec_b = (const float*)d_in[9];
  const float* dec_emb = (const float*)d_in[10];
  const float* dec_Wih = (const float*)d_in[11];
  const float* dec_bih = (const float*)d_in[12];
  const float* dec_Whh = (const float*)d_in[13];
  const float* dec_bhh = (const float*)d_in[14];
  const float* dec_fcW = (const float*)d_in[15];
  const float* dec_fcb = (const float*)d_in[16];
  float* out = (float*)d_out;

  float* ws = (float*)d_ws;
  size_t off = 0;
  float* wihT_e = ws + off; off += 393216;
  float* wihT_d = ws + off; off += 393216;
  float* gx_e = ws + off; off += 3145728;
  float* gx_d = ws + off; off += 3121152;
  float* hbuf = ws + off; off += 16384;
  float* zbuf = ws + off; off += 2048;
  int* cnt_e = (int*)(ws + off); off += 64;   // two counters, separate cachelines
  int* cnt_d = cnt_e + 32;
  unsigned short* hseq_bf = (unsigned short*)(ws + off); off += 524288;
  size_t wbf_elems = (size_t)Vv * Hh;
  bool use_wbf = (off + wbf_elems / 2) * sizeof(float) <= ws_size;
  unsigned short* wbf = (unsigned short*)(ws + off);

  // init
  hipMemsetAsync(cnt_e, 0, 64 * sizeof(int), stream);
  k_zero<<<(Bb * Hh + 255) / 256, 256, 0, stream>>>(hbuf, Bb * Hh);
  k_zero_first<<<(Bb * Vv + 255) / 256, 256, 0, stream>>>(out);

  if (use_wbf)
    k_cvt_bf16<<<(int)((wbf_elems / 4 + 255) / 256), 256, 0, stream>>>(
        dec_fcW, wbf, (int)(wbf_elems / 4));

  dim3 tb(32, 8);
  k_transpose<<<dim3(256 / 32, 1536 / 32), tb, 0, stream>>>(enc_Wih, wihT_e, 1536, 256);
  k_transpose<<<dim3(256 / 32, 1536 / 32), tb, 0, stream>>>(dec_Wih, wihT_d, 1536, 256);

  k_gx<<<dim3(128, 6), 256, 0, stream>>>(x, enc_emb, wihT_e, enc_bih, gx_e);
  k_gx<<<dim3(127, 6), 256, 0, stream>>>(x, dec_emb, wihT_d, dec_bih, gx_d);

  // encoder scan
  k_scan<<<NWG, 256, 0, stream>>>(enc_Whh, enc_bhh, gx_e, hbuf,
                                  (unsigned short*)nullptr, 128, cnt_e);

  k_z<<<16, 128, 0, stream>>>(hbuf, fc_enc_W, fc_enc_b, zbuf, out + (size_t)Bb * Tt * Vv);
  k_hid0<<<16, 512, 0, stream>>>(zbuf, fc_dec_W, fc_dec_b, hbuf);

  // decoder scan
  k_scan<<<NWG, 256, 0, stream>>>(dec_Whh, dec_bhh, gx_d, hbuf, hseq_bf, 127, cnt_d);

  // logits
  if (use_wbf)
    k_logits_mfma<true><<<dim3(Vv / 64, 8), 256, 0, stream>>>(hseq_bf, wbf, dec_fcW,
                                                              dec_fcb, out);
  else
    k_logits_mfma<false><<<dim3(Vv / 64, 8), 256, 0, stream>>>(hseq_bf, (unsigned short*)nullptr,
                                                               dec_fcW, dec_fcb, out);
}